// Round 1
// baseline (112.920 us; speedup 1.0000x reference)
//
#include <hip/hip_runtime.h>

// Cox proportional hazards loss, N=8192, fp32.
// risk[i] = sum_j (survtime[j] >= survtime[i]) * exp(theta[j])
// loss    = -(1/N) * sum_i (theta[i] - log(risk[i])) * censor[i]
//
// Strategy: split j 8-way across blocks (inner loop = 1024 iters/thread),
// one thread per i, LDS-staged (survtime_j, exp theta_j) broadcast reads,
// fp32 atomicAdd merge into ws, tiny single-block finalize kernel.

#define COX_N 8192
#define TI 256          // i's per block (one per thread)
#define TJ 1024         // j's per block tile
#define NJT (COX_N / TJ) // 8 j-tiles
#define NIT (COX_N / TI) // 32 i-tiles

__global__ __launch_bounds__(TI) void cox_partial(const float* __restrict__ y,
                                                  const float* __restrict__ theta,
                                                  float* __restrict__ risk) {
    __shared__ float2 s[TJ];  // (survtime_j, exp(theta_j))
    const int t  = threadIdx.x;
    const int bi = blockIdx.x & (NIT - 1);  // i-tile
    const int bj = blockIdx.x / NIT;        // j-tile
    const int j0 = bj * TJ;

    // Stage this block's j-chunk into LDS (4 elements/thread).
    for (int k = t; k < TJ; k += TI) {
        const int j = j0 + k;
        s[k] = make_float2(y[2 * j], __expf(theta[j]));
    }
    __syncthreads();

    const int   i    = bi * TI + t;
    const float st_i = y[2 * i];
    float acc = 0.f;
#pragma unroll 16
    for (int k = 0; k < TJ; ++k) {
        // broadcast LDS read (all lanes same addr) -> no bank conflicts
        acc += (s[k].x >= st_i) ? s[k].y : 0.f;
    }
    atomicAdd(&risk[i], acc);
}

__global__ __launch_bounds__(1024) void cox_finalize(const float* __restrict__ y,
                                                     const float* __restrict__ theta,
                                                     const float* __restrict__ risk,
                                                     float* __restrict__ out) {
    const int t = threadIdx.x;
    float local = 0.f;
    for (int i = t; i < COX_N; i += 1024) {
        const float censor = (y[2 * i + 1] != 0.f) ? 1.f : 0.f;
        local += (theta[i] - __logf(risk[i])) * censor;
    }
    // wave64 reduce
    for (int off = 32; off > 0; off >>= 1)
        local += __shfl_down(local, off, 64);
    __shared__ float red[16];
    if ((t & 63) == 0) red[t >> 6] = local;
    __syncthreads();
    if (t == 0) {
        float s2 = 0.f;
        for (int w = 0; w < 16; ++w) s2 += red[w];
        out[0] = -s2 / (float)COX_N;
    }
}

extern "C" void kernel_launch(void* const* d_in, const int* in_sizes, int n_in,
                              void* d_out, int out_size, void* d_ws, size_t ws_size,
                              hipStream_t stream) {
    const float* y     = (const float*)d_in[0];  // (N,2): [survtime, censor]
    const float* theta = (const float*)d_in[1];  // (N,1)
    float* risk = (float*)d_ws;                  // N floats = 32 KB scratch
    float* out  = (float*)d_out;

    hipMemsetAsync(risk, 0, COX_N * sizeof(float), stream);
    cox_partial<<<dim3(NIT * NJT), dim3(TI), 0, stream>>>(y, theta, risk);
    cox_finalize<<<dim3(1), dim3(1024), 0, stream>>>(y, theta, risk, out);
}

// Round 2
// 64.300 us; speedup vs baseline: 1.7561x; 1.7561x over previous
//
#include <hip/hip_runtime.h>

// Cox PH loss, N=8192 fp32.
// R2: register-blocked (8 i's/thread in regs), 1024 blocks x 256 thr
// (4 blocks/CU -> 16 waves/CU), j scanned coalesced from global (L2-resident),
// per-block partial to ws, tiny finalize. No atomics, no memset.

#define COX_N 8192
#define TPB   256
#define IPB   8                 // i's owned per block (register-blocked per thread)
#define NBLK  (COX_N / IPB)     // 1024 blocks
#define JPT   (COX_N / TPB)     // 32 j-iterations per thread
#define NWAVE (TPB / 64)        // 4 waves per block

__global__ __launch_bounds__(TPB, 4) void cox_main(const float* __restrict__ y,
                                                   const float* __restrict__ theta,
                                                   float* __restrict__ partial) {
    const int t  = threadIdx.x;
    const int b  = blockIdx.x;
    const int i0 = b * IPB;

    __shared__ float s_st[IPB];
    __shared__ float s_red[IPB][NWAVE];

    if (t < IPB) s_st[t] = y[2 * (i0 + t)];
    __syncthreads();

    float st[IPB], acc[IPB];
#pragma unroll
    for (int r = 0; r < IPB; ++r) { st[r] = s_st[r]; acc[r] = 0.f; }

    // Scan all j; thread t handles j = t + k*TPB (coalesced). Each loaded j
    // updates 8 independent accumulator chains (ILP hides dep latency).
#pragma unroll 4
    for (int k = 0; k < JPT; ++k) {
        const int   j   = t + k * TPB;
        const float stj = y[2 * j];
        const float e   = __expf(theta[j]);
#pragma unroll
        for (int r = 0; r < IPB; ++r)
            acc[r] += (stj >= st[r]) ? e : 0.f;
    }

    // Wave-level reduce each of the 8 accumulators, then cross-wave via LDS.
    const int lane = t & 63, wave = t >> 6;
#pragma unroll
    for (int r = 0; r < IPB; ++r) {
        float v = acc[r];
        for (int off = 32; off > 0; off >>= 1)
            v += __shfl_down(v, off, 64);
        if (lane == 0) s_red[r][wave] = v;
    }
    __syncthreads();

    // Wave 0: lanes 0..7 finish their i; reduce 8 terms; one store per block.
    if (wave == 0) {
        float term = 0.f;
        if (t < IPB) {
            float risk = 0.f;
#pragma unroll
            for (int w = 0; w < NWAVE; ++w) risk += s_red[t][w];
            const int   i      = i0 + t;
            const float censor = (y[2 * i + 1] != 0.f) ? 1.f : 0.f;
            term = (theta[i] - __logf(risk)) * censor;
        }
        term += __shfl_down(term, 4, 64);
        term += __shfl_down(term, 2, 64);
        term += __shfl_down(term, 1, 64);
        if (t == 0) partial[b] = term;
    }
}

__global__ __launch_bounds__(TPB) void cox_fin(const float* __restrict__ partial,
                                               float* __restrict__ out) {
    const int t = threadIdx.x;
    float v = partial[t] + partial[t + 256] + partial[t + 512] + partial[t + 768];
    for (int off = 32; off > 0; off >>= 1)
        v += __shfl_down(v, off, 64);
    __shared__ float red[NWAVE];
    if ((t & 63) == 0) red[t >> 6] = v;
    __syncthreads();
    if (t == 0) out[0] = -(red[0] + red[1] + red[2] + red[3]) / (float)COX_N;
}

extern "C" void kernel_launch(void* const* d_in, const int* in_sizes, int n_in,
                              void* d_out, int out_size, void* d_ws, size_t ws_size,
                              hipStream_t stream) {
    const float* y     = (const float*)d_in[0];  // (N,2): [survtime, censor]
    const float* theta = (const float*)d_in[1];  // (N,1)
    float* part = (float*)d_ws;                  // NBLK floats = 4 KB scratch
    float* out  = (float*)d_out;

    cox_main<<<dim3(NBLK), dim3(TPB), 0, stream>>>(y, theta, part);
    cox_fin<<<dim3(1), dim3(TPB), 0, stream>>>(part, out);
}